// Round 12
// baseline (707.314 us; speedup 1.0000x reference)
//
#include <hip/hip_runtime.h>
#include <hip/hip_cooperative_groups.h>
#include <cstdint>
#include <cstddef>

namespace cg = cooperative_groups;

#define TPB 256
#define CAP 128   // bucket capacity per node (mean degree 16)

typedef __bf16 bf16x8 __attribute__((ext_vector_type(8)));
typedef float f32x4 __attribute__((ext_vector_type(4)));

union FragU { ushort u[8]; uint4 q; bf16x8 v; };

__device__ __forceinline__ ushort f2bf(float f)
{
    union { float f; uint32_t u; } v; v.f = f;
    uint32_t r = v.u + 0x7FFFu + ((v.u >> 16) & 1u);   // RNE
    return (ushort)(r >> 16);
}

// ---------------- stage bodies (R10-proven math) ----------------

__device__ __forceinline__ void prep_body(
    int bx, const float* __restrict__ lat, const float* __restrict__ W,
    const float* __restrict__ bias, float* __restrict__ out, int* __restrict__ cnt)
{
    if (bx < 512) {
        int tid = bx * TPB + threadIdx.x;   // 131072
        int c = tid & 63, b = (tid >> 6) & 7, n = tid >> 9;
        int j = n * 64 + c;
        float acc = bias[j];
        const float* lb = lat + b * 64;
#pragma unroll 16
        for (int l = 0; l < 64; ++l)
            acc = fmaf(lb[l], W[l * 16384 + j], acc);
        out[tid] = acc;
    } else {
        int tid = (bx - 512) * TPB + threadIdx.x;
        if (tid < 21504) cnt[tid] = 0;
    }
}

__device__ __forceinline__ void build_body(
    int bx,
    const int* __restrict__ r0, const int* __restrict__ c0, const float* __restrict__ v0,
    const int* __restrict__ r1, const int* __restrict__ c1, const float* __restrict__ v1,
    const int* __restrict__ r2, const int* __restrict__ c2, const float* __restrict__ v2,
    int* __restrict__ cnt, int2* __restrict__ ecv,
    const float* __restrict__ X,
    const float* __restrict__ W0, const float* __restrict__ Ub0,
    const float* __restrict__ W1, const float* __restrict__ Ub1,
    const float* __restrict__ W2, const float* __restrict__ Ub2,
    ushort* __restrict__ Fq,
    float* __restrict__ UbW0, float* __restrict__ UbW1, float* __restrict__ UbW2)
{
    if (bx < 1344) {
        int e = bx * TPB + threadIdx.x;      // 344064 edges
        int node, col; float val;
        if (e < 16384)      { node = r0[e];                 col = c0[e]; val = v0[e]; }
        else if (e < 81920) { int l = e - 16384; node = 1024 + r1[l]; col = c1[l]; val = v1[l]; }
        else                { int l = e - 81920; node = 5120 + r2[l]; col = c2[l]; val = v2[l]; }
        int pos = atomicAdd(&cnt[node], 1);
        ecv[(size_t)node * CAP + pos] = make_int2(col, __float_as_int(val));
    } else if (bx < 1856) {
        // fold0: F0 = feat0@W0 in MFMA B-frag order (KF=256)
        int tid = (bx - 1344) * TPB + threadIdx.x;
        int co = tid % 64, nb = tid / 64;
        const float* x = X + (size_t)nb * 64;
        float acc = 0.f;
#pragma unroll
        for (int ci = 0; ci < 64; ++ci) acc = fmaf(x[ci], W0[ci * 64 + co], acc);
        int n = nb >> 3, bb = nb & 7;
        int col = bb * 64 + co;
        int ks = n >> 5, rr = n & 31, kq = rr >> 3, j = rr & 7;
        int ct = col >> 4, cl = col & 15;
        size_t idx = ((((size_t)ct * 8 + ks) * 4 + kq) * 16 + cl) * 8 + j;
        Fq[idx] = f2bf(acc);
    } else if (bx < 2112) {
        int tid = (bx - 1856) * TPB + threadIdx.x;   // 65536 = 1024x64
        int co = tid % 64, row = tid / 64;
        const float* x = Ub0 + (size_t)row * 64;
        float acc = 0.f;
#pragma unroll
        for (int ci = 0; ci < 64; ++ci) acc = fmaf(x[ci], W0[ci * 64 + co], acc);
        UbW0[tid] = acc;
    } else if (bx < 2624) {
        int tid = (bx - 2112) * TPB + threadIdx.x;   // 131072 = 4096x32
        int co = tid % 32, row = tid / 32;
        const float* x = Ub1 + (size_t)row * 64;
        float acc = 0.f;
#pragma unroll
        for (int ci = 0; ci < 64; ++ci) acc = fmaf(x[ci], W1[ci * 32 + co], acc);
        UbW1[tid] = acc;
    } else {
        int tid = (bx - 2624) * TPB + threadIdx.x;   // 49152 = 16384x3
        int co = tid % 3, row = tid / 3;
        const float* x = Ub2 + (size_t)row * 32;
        float acc = 0.f;
#pragma unroll
        for (int ci = 0; ci < 32; ++ci) acc = fmaf(x[ci], W2[ci * 3 + co], acc);
        UbW2[tid] = acc;
    }
}

// fused gather + relu/bias + fold-to-frags (no tail; UbW folds live in build)
template<int NPB, int BCIN, int CI, int CO, int COLS, int KF, int RBASE>
__device__ __forceinline__ void gf_body(
    const float* __restrict__ up, const int* __restrict__ cnt,
    const int2* __restrict__ ecv, const float* __restrict__ bias,
    const float* __restrict__ W, ushort* __restrict__ Fq,
    int bx, char* smem)
{
    constexpr int TPN = TPB / NPB;
    constexpr int CPT = BCIN / TPN;
    float* feat = (float*)smem;            // NPB*BCIN
    float* Wl   = feat + NPB * BCIN;       // CI*CO
    const int tid = threadIdx.x;
#pragma unroll
    for (int i = tid; i < CI * CO; i += TPB) Wl[i] = W[i];

    const int ni = tid / TPN;
    const int li = tid % TPN;
    const int node = bx * NPB + ni;
    const int deg = cnt[RBASE + node];
    const int2* ep = ecv + (size_t)(RBASE + node) * CAP;

    float acc[CPT];
#pragma unroll
    for (int k = 0; k < CPT; ++k) acc[k] = 0.f;
    for (int p = 0; p < deg; ++p) {
        int2 cv = ep[p];
        float v = __int_as_float(cv.y);
        const float* ur = up + (size_t)cv.x * BCIN + li;
#pragma unroll
        for (int k = 0; k < CPT; ++k)
            acc[k] = fmaf(v, ur[k * TPN], acc[k]);
    }
#pragma unroll
    for (int k = 0; k < CPT; ++k) {
        int c = li + k * TPN;
        feat[ni * BCIN + c] = fmaxf(acc[k] + bias[c % CI], 0.f);
    }
    __syncthreads();

#pragma unroll
    for (int e = tid; e < NPB * COLS; e += TPB) {
        int fni = e / COLS;
        int colp = e % COLS;
        int n = bx * NPB + fni;
        float a = 0.f;
        if (colp < 8 * CO) {
            int b = colp / CO, co = colp % CO;
            const float* fb = feat + fni * BCIN + b * CI;
#pragma unroll
            for (int ci = 0; ci < CI; ++ci)
                a = fmaf(fb[ci], Wl[ci * CO + co], a);
        }
        int ks = n >> 5, rr = n & 31, kq = rr >> 3, j = rr & 7;
        int ct = colp >> 4, cl = colp & 15;
        size_t idx = ((((size_t)ct * (KF / 32) + ks) * 4 + kq) * 16 + cl) * 8 + j;
        Fq[idx] = f2bf(a);
    }
}

// LDS-free MFMA GEMM, intra-block wave K-split, 2-deep pipeline (R10 config)
#define LOAD_STEP(S, t)                                                     \
    if ((t) < KS) {                                                         \
        _Pragma("unroll")                                                   \
        for (int rf = 0; rf < RF; ++rf) {                                   \
            a[S][rf][0] = *reinterpret_cast<const float4*>(Ap[rf] + (t) * 32);     \
            a[S][rf][1] = *reinterpret_cast<const float4*>(Ap[rf] + (t) * 32 + 4); \
        }                                                                   \
        _Pragma("unroll")                                                   \
        for (int cf = 0; cf < CF; ++cf)                                     \
            b[S][cf] = *reinterpret_cast<const uint4*>(Bp[cf] + (t) * 512); \
    }

#define COMP_STEP(S)                                                        \
    {                                                                       \
        _Pragma("unroll")                                                   \
        for (int rf = 0; rf < RF; ++rf) {                                   \
            const float* fa = reinterpret_cast<const float*>(&a[S][rf][0]); \
            bf16x8 av;                                                      \
            _Pragma("unroll")                                               \
            for (int j = 0; j < 8; ++j) av[j] = (__bf16)fa[j];              \
            _Pragma("unroll")                                               \
            for (int cf = 0; cf < CF; ++cf) {                               \
                FragU bfr; bfr.q = b[S][cf];                                \
                acc[rf][cf] = __builtin_amdgcn_mfma_f32_16x16x32_bf16(      \
                    av, bfr.v, acc[rf][cf], 0, 0, 0);                       \
            }                                                               \
        }                                                                   \
    }

template<int K, int NTOT, int CO, int CF, int RF>
__device__ __forceinline__ void gemm_body(
    const float* __restrict__ U, const ushort* __restrict__ Fq,
    const float* __restrict__ UbW, float* __restrict__ up,
    int bxr, int jt, char* smem)
{
    constexpr int KCH = K / 4;
    constexpr int KS = KCH / 32;
    constexpr int NC = CF * 16;
    constexpr int RED = RF * NC * 16;
    static_assert(KS % 2 == 0, "even k-steps");
    float* red = (float*)smem;   // [4][RED], <=32KB

    const int tid = threadIdx.x;
    const int lane = tid & 63;
    const int w = tid >> 6;
    const int rowbase = bxr * (RF * 16);
    const int kq = lane >> 4;
    const int m = lane & 15;

    const float* Ap[RF];
#pragma unroll
    for (int rf = 0; rf < RF; ++rf)
        Ap[rf] = U + (size_t)(rowbase + rf * 16 + m) * K + w * KCH + kq * 8;

    const ushort* Bp[CF];
#pragma unroll
    for (int cf = 0; cf < CF; ++cf)
        Bp[cf] = Fq + ((size_t)(jt * CF + cf) * (K / 32) + (size_t)w * KS) * 512
                 + lane * 8;

    f32x4 acc[RF][CF];
#pragma unroll
    for (int rf = 0; rf < RF; ++rf)
#pragma unroll
        for (int cf = 0; cf < CF; ++cf)
            acc[rf][cf] = (f32x4){0.f, 0.f, 0.f, 0.f};

    float4 a[2][RF][2];
    uint4  b[2][CF];

    LOAD_STEP(0, 0)
#pragma unroll
    for (int t = 0; t < KS; t += 2) {
        LOAD_STEP(1, t + 1)
        COMP_STEP(0)
        LOAD_STEP(0, t + 2)
        COMP_STEP(1)
    }

#pragma unroll
    for (int rf = 0; rf < RF; ++rf)
#pragma unroll
        for (int cf = 0; cf < CF; ++cf)
#pragma unroll
            for (int r = 0; r < 4; ++r)
                red[w * RED + (rf * NC + cf * 16 + m) * 16 + kq * 4 + r] = acc[rf][cf][r];
    __syncthreads();

#pragma unroll
    for (int e = tid; e < RED; e += TPB) {
        int rf = e / (NC * 16);
        int rem = e - rf * (NC * 16);
        int col = rem >> 4, row = rem & 15;
        float v = red[0 * RED + e] + red[1 * RED + e] + red[2 * RED + e] + red[3 * RED + e];
        int gcol = jt * NC + col;
        int grow = rowbase + rf * 16 + row;
        if (gcol < NTOT)
            up[(size_t)grow * NTOT + gcol] =
                v + UbW[(size_t)grow * CO + gcol % CO];
    }
}
#undef LOAD_STEP
#undef COMP_STEP

template<int BC, int CO, int NR, int RBASE>
__device__ __forceinline__ void gout_body(
    const float* __restrict__ up, const int* __restrict__ cnt,
    const int2* __restrict__ ecv, const float* __restrict__ bias,
    float* __restrict__ out, int bx)
{
    constexpr int JQ = BC / 4;
    int tid = bx * TPB + threadIdx.x;
    if (tid < NR * JQ) {
        int jq = tid % JQ;
        int r = tid / JQ;
        int deg = cnt[RBASE + r];
        const int2* ep = ecv + (size_t)(RBASE + r) * CAP;
        float4 acc = make_float4(0.f, 0.f, 0.f, 0.f);
        for (int p = 0; p < deg; ++p) {
            int2 cv = ep[p];
            float v = __int_as_float(cv.y);
            float4 u = *reinterpret_cast<const float4*>(&up[(size_t)cv.x * BC + jq * 4]);
            acc.x = fmaf(v, u.x, acc.x);
            acc.y = fmaf(v, u.y, acc.y);
            acc.z = fmaf(v, u.z, acc.z);
            acc.w = fmaf(v, u.w, acc.w);
        }
        int col0 = jq * 4;
        float av[4] = {acc.x, acc.y, acc.z, acc.w};
#pragma unroll
        for (int e = 0; e < 4; ++e) {
            int col = col0 + e;
            int b = col / 3, j = col - b * 3;
            out[(size_t)b * 49152 + (size_t)r * 3 + j] = fmaxf(av[e] + bias[j], 0.f);
        }
    }
}

// ---------------- args + mega kernel ----------------
struct MegaArgs {
    const float *lat, *fcW, *fcb;
    const float *U0, *Ub0, *W0, *b0, *vals0; const int *rows0, *cols0;
    const float *U1, *Ub1, *W1, *b1, *vals1; const int *rows1, *cols1;
    const float *U2, *Ub2, *W2, *b2, *vals2; const int *rows2, *cols2;
    float* fbuf0; ushort* Fq; float *UbW0, *UbW1, *UbW2; float* up;
    int* cnt; int2* ecv; float* out;
};

__global__ __launch_bounds__(TPB, 2) void k_mega(MegaArgs A)
{
    cg::grid_group grid = cg::this_grid();
    __shared__ __align__(16) char smem[32768];
    const int G = gridDim.x;

    // S1: fc + zero cnt (596)
    for (int bx = blockIdx.x; bx < 596; bx += G)
        prep_body(bx, A.lat, A.fcW, A.fcb, A.fbuf0, A.cnt);
    __threadfence(); grid.sync(); __threadfence();

    // S2: bucket build + fold0 + UbW0/1/2 (2816)
    for (int bx = blockIdx.x; bx < 2816; bx += G)
        build_body(bx, A.rows0, A.cols0, A.vals0, A.rows1, A.cols1, A.vals1,
                   A.rows2, A.cols2, A.vals2, A.cnt, A.ecv, A.fbuf0,
                   A.W0, A.Ub0, A.W1, A.Ub1, A.W2, A.Ub2,
                   A.Fq, A.UbW0, A.UbW1, A.UbW2);
    __threadfence(); grid.sync(); __threadfence();

    // S3: gemm0 (64x4 = 256 tiles)
    for (int t = blockIdx.x; t < 256; t += G) {
        gemm_body<256, 512, 64, 8, 1>(A.U0, A.Fq, A.UbW0, A.up, t & 63, t >> 6, smem);
        __syncthreads();
    }
    __threadfence(); grid.sync(); __threadfence();

    // S4: gf0 (1024)
    for (int bx = blockIdx.x; bx < 1024; bx += G) {
        gf_body<1, 512, 64, 32, 256, 1024, 0>(A.up, A.cnt, A.ecv, A.b0, A.W1, A.Fq, bx, smem);
        __syncthreads();
    }
    __threadfence(); grid.sync(); __threadfence();

    // S5: gemm1 (256x2 = 512 tiles)
    for (int t = blockIdx.x; t < 512; t += G) {
        gemm_body<1024, 256, 32, 8, 1>(A.U1, A.Fq, A.UbW1, A.up, t & 255, t >> 8, smem);
        __syncthreads();
    }
    __threadfence(); grid.sync(); __threadfence();

    // S6: gf1 (512)
    for (int bx = blockIdx.x; bx < 512; bx += G) {
        gf_body<8, 256, 32, 3, 32, 4096, 1024>(A.up, A.cnt, A.ecv, A.b1, A.W2, A.Fq, bx, smem);
        __syncthreads();
    }
    __threadfence(); grid.sync(); __threadfence();

    // S7: gemm2 (512 tiles, RF=2 CF=2)
    for (int t = blockIdx.x; t < 512; t += G) {
        gemm_body<4096, 24, 3, 2, 2>(A.U2, A.Fq, A.UbW2, A.up, t, 0, smem);
        __syncthreads();
    }
    __threadfence(); grid.sync(); __threadfence();

    // S8: gather_out (384)
    for (int bx = blockIdx.x; bx < 384; bx += G)
        gout_body<24, 3, 16384, 5120>(A.up, A.cnt, A.ecv, A.b2, A.out, bx);
}

// ---------------- fallback wrappers (8-kernel path) ----------------
__global__ __launch_bounds__(TPB) void k_prep_g(
    const float* lat, const float* fcW, const float* fcb, float* fbuf0, int* cnt)
{ prep_body(blockIdx.x, lat, fcW, fcb, fbuf0, cnt); }

__global__ __launch_bounds__(TPB) void k_build_g(
    const int* r0, const int* c0, const float* v0,
    const int* r1, const int* c1, const float* v1,
    const int* r2, const int* c2, const float* v2,
    int* cnt, int2* ecv, const float* X,
    const float* W0, const float* Ub0, const float* W1, const float* Ub1,
    const float* W2, const float* Ub2,
    ushort* Fq, float* UbW0, float* UbW1, float* UbW2)
{ build_body(blockIdx.x, r0, c0, v0, r1, c1, v1, r2, c2, v2, cnt, ecv, X,
             W0, Ub0, W1, Ub1, W2, Ub2, Fq, UbW0, UbW1, UbW2); }

template<int K, int NTOT, int CO, int CF, int RF>
__global__ __launch_bounds__(TPB) void k_gemm_g(
    const float* U, const ushort* Fq, const float* UbW, float* up)
{
    __shared__ __align__(16) char smem[32768];
    gemm_body<K, NTOT, CO, CF, RF>(U, Fq, UbW, up, blockIdx.x, blockIdx.y, smem);
}

template<int NPB, int BCIN, int CI, int CO, int COLS, int KF, int RBASE>
__global__ __launch_bounds__(TPB) void k_gf_g(
    const float* up, const int* cnt, const int2* ecv,
    const float* bias, const float* W, ushort* Fq)
{
    __shared__ __align__(16) char smem[32768];
    gf_body<NPB, BCIN, CI, CO, COLS, KF, RBASE>(up, cnt, ecv, bias, W, Fq, blockIdx.x, smem);
}

template<int BC, int CO, int NR, int RBASE>
__global__ __launch_bounds__(TPB) void k_gout_g(
    const float* up, const int* cnt, const int2* ecv, const float* bias, float* out)
{ gout_body<BC, CO, NR, RBASE>(up, cnt, ecv, bias, out, blockIdx.x); }

extern "C" void kernel_launch(void* const* d_in, const int* in_sizes, int n_in,
                              void* d_out, int out_size, void* d_ws, size_t ws_size,
                              hipStream_t stream)
{
    const float* lat   = (const float*)d_in[0];
    const float* fcW   = (const float*)d_in[1];
    const float* fcb   = (const float*)d_in[2];
    const float* U0    = (const float*)d_in[3];
    const float* Ub0   = (const float*)d_in[4];
    const float* W0    = (const float*)d_in[5];
    const float* b0    = (const float*)d_in[6];
    const float* vals0 = (const float*)d_in[7];
    const int*   rows0 = (const int*)d_in[8];
    const int*   cols0 = (const int*)d_in[9];
    const float* U1    = (const float*)d_in[10];
    const float* Ub1   = (const float*)d_in[11];
    const float* W1    = (const float*)d_in[12];
    const float* b1    = (const float*)d_in[13];
    const float* vals1 = (const float*)d_in[14];
    const int*   rows1 = (const int*)d_in[15];
    const int*   cols1 = (const int*)d_in[16];
    const float* U2    = (const float*)d_in[17];
    const float* Ub2   = (const float*)d_in[18];
    const float* W2    = (const float*)d_in[19];
    const float* b2    = (const float*)d_in[20];
    const float* vals2 = (const float*)d_in[21];
    const int*   rows2 = (const int*)d_in[22];
    const int*   cols2 = (const int*)d_in[23];

    float* ws = (float*)d_ws;
    float*  fbuf0 = ws;                        // 131072
    float*  fWq   = fbuf0 + 131072;            // 262144
    float*  UbW0  = fWq + 262144;              // 65536
    float*  UbW1  = UbW0 + 65536;              // 131072
    float*  UbW2  = UbW1 + 131072;             // 49152
    float*  up    = UbW2 + 49152;              // 1048576
    int*    cnt   = (int*)(up + 1048576);      // 21504 (+4 pad)
    int2*   ecv   = (int2*)(cnt + 21508);      // 21504*128 int2

    ushort* Fq16 = (ushort*)fWq;
    float* out = (float*)d_out;

    MegaArgs A;
    A.lat = lat; A.fcW = fcW; A.fcb = fcb;
    A.U0 = U0; A.Ub0 = Ub0; A.W0 = W0; A.b0 = b0; A.vals0 = vals0; A.rows0 = rows0; A.cols0 = cols0;
    A.U1 = U1; A.Ub1 = Ub1; A.W1 = W1; A.b1 = b1; A.vals1 = vals1; A.rows1 = rows1; A.cols1 = cols1;
    A.U2 = U2; A.Ub2 = Ub2; A.W2 = W2; A.b2 = b2; A.vals2 = vals2; A.rows2 = rows2; A.cols2 = cols2;
    A.fbuf0 = fbuf0; A.Fq = Fq16; A.UbW0 = UbW0; A.UbW1 = UbW1; A.UbW2 = UbW2;
    A.up = up; A.cnt = cnt; A.ecv = ecv; A.out = out;

    // cooperative mega-kernel path
    int nbpc = 0;
    hipError_t oe = hipOccupancyMaxActiveBlocksPerMultiprocessor(&nbpc, k_mega, TPB, 0);
    int G = (oe == hipSuccess && nbpc > 0) ? nbpc * 256 : 0;
    if (G > 1024) G = 1024;
    if (G >= 256) {
        void* kargs[] = { (void*)&A };
        hipError_t ce = hipLaunchCooperativeKernel(k_mega, dim3(G), dim3(TPB),
                                                   kargs, 0, stream);
        if (ce == hipSuccess) return;
    }

    // fallback: 8-kernel path (R10 structure)
    hipLaunchKernelGGL(k_prep_g, dim3(596), dim3(TPB), 0, stream, lat, fcW, fcb, fbuf0, cnt);
    hipLaunchKernelGGL(k_build_g, dim3(2816), dim3(TPB), 0, stream,
                       rows0, cols0, vals0, rows1, cols1, vals1, rows2, cols2, vals2,
                       cnt, ecv, fbuf0, W0, Ub0, W1, Ub1, W2, Ub2, Fq16, UbW0, UbW1, UbW2);
    hipLaunchKernelGGL((k_gemm_g<256, 512, 64, 8, 1>), dim3(64, 4), dim3(TPB), 0, stream,
                       U0, Fq16, UbW0, up);
    hipLaunchKernelGGL((k_gf_g<1, 512, 64, 32, 256, 1024, 0>), dim3(1024), dim3(TPB), 0, stream,
                       up, cnt, ecv, b0, W1, Fq16);
    hipLaunchKernelGGL((k_gemm_g<1024, 256, 32, 8, 1>), dim3(256, 2), dim3(TPB), 0, stream,
                       U1, Fq16, UbW1, up);
    hipLaunchKernelGGL((k_gf_g<8, 256, 32, 3, 32, 4096, 1024>), dim3(512), dim3(TPB), 0, stream,
                       up, cnt, ecv, b1, W2, Fq16);
    hipLaunchKernelGGL((k_gemm_g<4096, 24, 3, 2, 2>), dim3(512, 1), dim3(TPB), 0, stream,
                       U2, Fq16, UbW2, up);
    hipLaunchKernelGGL((k_gout_g<24, 3, 16384, 5120>), dim3(384), dim3(TPB), 0, stream,
                       up, cnt, ecv, b2, out);
}

// Round 13
// 155.953 us; speedup vs baseline: 4.5354x; 4.5354x over previous
//
#include <hip/hip_runtime.h>
#include <cstdint>
#include <cstddef>

#define TPB 256
#define CAP 128   // bucket capacity per node (mean degree 16)

typedef __bf16 bf16x8 __attribute__((ext_vector_type(8)));
typedef float f32x4 __attribute__((ext_vector_type(4)));

union FragU { ushort u[8]; uint4 q; bf16x8 v; };

__device__ __forceinline__ ushort f2bf(float f)
{
    union { float f; uint32_t u; } v; v.f = f;
    uint32_t r = v.u + 0x7FFFu + ((v.u >> 16) & 1u);   // RNE
    return (ushort)(r >> 16);
}

// prep: fc (blocks 0..511) + zero cnt (blocks 512..595)
__global__ __launch_bounds__(TPB) void k_prep(
    const float* __restrict__ lat, const float* __restrict__ W,
    const float* __restrict__ bias, float* __restrict__ out,
    int* __restrict__ cnt)
{
    int bx = blockIdx.x;
    if (bx < 512) {
        int tid = bx * TPB + threadIdx.x;   // 131072
        int c = tid & 63;
        int b = (tid >> 6) & 7;
        int n = tid >> 9;
        int j = n * 64 + c;
        float acc = bias[j];
        const float* lb = lat + b * 64;
#pragma unroll 16
        for (int l = 0; l < 64; ++l)
            acc = fmaf(lb[l], W[l * 16384 + j], acc);
        out[tid] = acc;
    } else {
        int tid = (bx - 512) * TPB + threadIdx.x;
        if (tid < 21504) cnt[tid] = 0;
    }
}

// build: blocks [0,1344) bucket-fill all 3 edge lists (packed int2);
//        blocks [1344,1856) fold0 F-frags; [1856,2112) UbW0 tail.
__global__ __launch_bounds__(TPB) void k_build(
    const int* __restrict__ r0, const int* __restrict__ c0, const float* __restrict__ v0,
    const int* __restrict__ r1, const int* __restrict__ c1, const float* __restrict__ v1,
    const int* __restrict__ r2, const int* __restrict__ c2, const float* __restrict__ v2,
    int* __restrict__ cnt, int2* __restrict__ ecv,
    const float* __restrict__ X, const float* __restrict__ W0,
    const float* __restrict__ Ub0,
    ushort* __restrict__ Fq, float* __restrict__ UbW)
{
    int bx = blockIdx.x;
    if (bx < 1344) {
        int e = bx * TPB + threadIdx.x;
        int node, col; float val;
        if (e < 16384)       { node = r0[e];                col = c0[e];  val = v0[e]; }
        else if (e < 81920)  { int l = e - 16384; node = 1024 + r1[l]; col = c1[l]; val = v1[l]; }
        else                 { int l = e - 81920; node = 5120 + r2[l]; col = c2[l]; val = v2[l]; }
        int pos = atomicAdd(&cnt[node], 1);
        ecv[(size_t)node * CAP + pos] = make_int2(col, __float_as_int(val));
    } else if (bx < 1856) {
        // fold0: F = feat0@W0 in MFMA B-frag order, CI=64 CO=64 KF=256
        int tid = (bx - 1344) * TPB + threadIdx.x;
        int co = tid % 64;
        int nb = tid / 64;
        const float* x = X + (size_t)nb * 64;
        float acc = 0.f;
#pragma unroll
        for (int ci = 0; ci < 64; ++ci)
            acc = fmaf(x[ci], W0[ci * 64 + co], acc);
        int n = nb >> 3, bb = nb & 7;
        int col = bb * 64 + co;
        int ks = n >> 5, r = n & 31, kq = r >> 3, j = r & 7;
        int ct = col >> 4, cl = col & 15;
        size_t idx = ((((size_t)ct * (256 / 32) + ks) * 4 + kq) * 16 + cl) * 8 + j;
        Fq[idx] = f2bf(acc);
    } else {
        int tid = (bx - 1856) * TPB + threadIdx.x;
        if (tid >= 65536) return;
        int co = tid % 64;
        int row = tid / 64;
        const float* x = Ub0 + (size_t)row * 64;
        float acc = 0.f;
#pragma unroll
        for (int ci = 0; ci < 64; ++ci)
            acc = fmaf(x[ci], W0[ci * 64 + co], acc);
        UbW[tid] = acc;
    }
}

// ---------------- fused gather + relu/bias + fold-to-frags ----------------
// NPB nodes per block; TPN=TPB/NPB threads per node; CPT=BCIN/TPN ch/thread.
template<int NPB, int BCIN, int CI, int CO, int COLS, int KF,
         int NNODE, int RBASE, int NBUB>
__global__ __launch_bounds__(TPB) void k_gf(
    const float* __restrict__ up, const int* __restrict__ cnt,
    const int2* __restrict__ ecv,
    const float* __restrict__ bias, const float* __restrict__ W,
    const float* __restrict__ Ub,
    ushort* __restrict__ Fq, float* __restrict__ UbW)
{
    constexpr int TPN = TPB / NPB;
    constexpr int CPT = BCIN / TPN;
    int bx = blockIdx.x;
    if (bx < NNODE / NPB) {
        __shared__ float feat[NPB * BCIN];
        __shared__ float Wl[CI * CO];
        const int tid = threadIdx.x;
#pragma unroll
        for (int i = tid; i < CI * CO; i += TPB) Wl[i] = W[i];

        const int ni = tid / TPN;
        const int li = tid % TPN;
        const int node = bx * NPB + ni;
        const int deg = cnt[RBASE + node];
        const int2* ep = ecv + (size_t)(RBASE + node) * CAP;

        float acc[CPT];
#pragma unroll
        for (int k = 0; k < CPT; ++k) acc[k] = 0.f;
        for (int p = 0; p < deg; ++p) {
            int2 cv = ep[p];                       // broadcast within TPN group
            float v = __int_as_float(cv.y);
            const float* ur = up + (size_t)cv.x * BCIN + li;
#pragma unroll
            for (int k = 0; k < CPT; ++k)
                acc[k] = fmaf(v, ur[k * TPN], acc[k]);
        }
#pragma unroll
        for (int k = 0; k < CPT; ++k) {
            int c = li + k * TPN;
            feat[ni * BCIN + c] = fmaxf(acc[k] + bias[c % CI], 0.f);
        }
        __syncthreads();

#pragma unroll
        for (int e = tid; e < NPB * COLS; e += TPB) {
            int fni = e / COLS;
            int colp = e % COLS;
            int n = bx * NPB + fni;
            float a = 0.f;
            if (colp < 8 * CO) {
                int b = colp / CO, co = colp % CO;
                const float* fb = feat + fni * BCIN + b * CI;
#pragma unroll
                for (int ci = 0; ci < CI; ++ci)
                    a = fmaf(fb[ci], Wl[ci * CO + co], a);
            }
            int ks = n >> 5, rr = n & 31, kq = rr >> 3, j = rr & 7;
            int ct = colp >> 4, cl = colp & 15;
            size_t idx = ((((size_t)ct * (KF / 32) + ks) * 4 + kq) * 16 + cl) * 8 + j;
            Fq[idx] = f2bf(a);
        }
    } else {
        int tid = (bx - NNODE / NPB) * TPB + threadIdx.x;
        if (tid >= NBUB * CO) return;
        int co = tid % CO;
        int row = tid / CO;
        const float* x = Ub + (size_t)row * CI;
        float acc = 0.f;
#pragma unroll
        for (int ci = 0; ci < CI; ++ci)
            acc = fmaf(x[ci], W[ci * CO + co], acc);
        UbW[tid] = acc;
    }
}

// ---------------- LDS-free MFMA GEMM, intra-block wave K-split, PIPE-deep ----------------
template<int K, int NTOT, int CO, int CF, int RF, int PIPE>
__global__ __launch_bounds__(TPB) void k_gemm_ws(
    const float* __restrict__ U, const ushort* __restrict__ Fq,
    const float* __restrict__ UbW, float* __restrict__ up)
{
    constexpr int KCH = K / 4;
    constexpr int KS = KCH / 32;
    constexpr int NC = CF * 16;
    constexpr int RED = RF * NC * 16;

    __shared__ float red[4][RED];

    const int tid = threadIdx.x;
    const int lane = tid & 63;
    const int w = tid >> 6;
    const int rowbase = blockIdx.x * (RF * 16);
    const int jt = blockIdx.y;
    const int kq = lane >> 4;
    const int m = lane & 15;

    const float* Ap[RF];
#pragma unroll
    for (int rf = 0; rf < RF; ++rf)
        Ap[rf] = U + (size_t)(rowbase + rf * 16 + m) * K + w * KCH + kq * 8;

    const ushort* Bp[CF];
#pragma unroll
    for (int cf = 0; cf < CF; ++cf)
        Bp[cf] = Fq + ((size_t)(jt * CF + cf) * (K / 32) + (size_t)w * KS) * 512
                 + lane * 8;

    f32x4 acc[RF][CF];
#pragma unroll
    for (int rf = 0; rf < RF; ++rf)
#pragma unroll
        for (int cf = 0; cf < CF; ++cf)
            acc[rf][cf] = (f32x4){0.f, 0.f, 0.f, 0.f};

    float4 a[PIPE][RF][2];
    uint4  b[PIPE][CF];

#define LOAD_STEP(S, t)                                                     \
    if ((t) < KS) {                                                         \
        _Pragma("unroll")                                                   \
        for (int rf = 0; rf < RF; ++rf) {                                   \
            a[S][rf][0] = *reinterpret_cast<const float4*>(Ap[rf] + (t) * 32);     \
            a[S][rf][1] = *reinterpret_cast<const float4*>(Ap[rf] + (t) * 32 + 4); \
        }                                                                   \
        _Pragma("unroll")                                                   \
        for (int cf = 0; cf < CF; ++cf)                                     \
            b[S][cf] = *reinterpret_cast<const uint4*>(Bp[cf] + (t) * 512); \
    }

#define COMP_STEP(S)                                                        \
    {                                                                       \
        _Pragma("unroll")                                                   \
        for (int rf = 0; rf < RF; ++rf) {                                   \
            const float* fa = reinterpret_cast<const float*>(&a[S][rf][0]); \
            bf16x8 av;                                                      \
            _Pragma("unroll")                                               \
            for (int j = 0; j < 8; ++j) av[j] = (__bf16)fa[j];              \
            _Pragma("unroll")                                               \
            for (int cf = 0; cf < CF; ++cf) {                               \
                FragU bfr; bfr.q = b[S][cf];                                \
                acc[rf][cf] = __builtin_amdgcn_mfma_f32_16x16x32_bf16(      \
                    av, bfr.v, acc[rf][cf], 0, 0, 0);                       \
            }                                                               \
        }                                                                   \
    }

#pragma unroll
    for (int s = 0; s < PIPE; ++s) { LOAD_STEP(s, s) }
#pragma unroll
    for (int t = 0; t < KS; ++t) {
        COMP_STEP(t % PIPE)
        LOAD_STEP(t % PIPE, t + PIPE)
    }
#undef LOAD_STEP
#undef COMP_STEP

#pragma unroll
    for (int rf = 0; rf < RF; ++rf)
#pragma unroll
        for (int cf = 0; cf < CF; ++cf)
#pragma unroll
            for (int r = 0; r < 4; ++r)
                red[w][(rf * NC + cf * 16 + m) * 16 + kq * 4 + r] = acc[rf][cf][r];
    __syncthreads();

#pragma unroll
    for (int e = tid; e < RED; e += TPB) {
        int rf = e / (NC * 16);
        int rem = e - rf * (NC * 16);
        int col = rem >> 4, row = rem & 15;
        float v = red[0][e] + red[1][e] + red[2][e] + red[3][e];
        int gcol = jt * NC + col;
        int grow = rowbase + rf * 16 + row;
        if (gcol < NTOT)
            up[(size_t)grow * NTOT + gcol] =
                v + UbW[(size_t)grow * CO + gcol % CO];
    }
}

// ---------------- final gather: relu+bias + output transpose ----------------
template<int BC, int CO, int NR, int RBASE>
__global__ __launch_bounds__(TPB) void k_gather_out(
    const float* __restrict__ up, const int* __restrict__ cnt,
    const int2* __restrict__ ecv,
    const float* __restrict__ bias, float* __restrict__ out)
{
    constexpr int JQ = BC / 4;
    int tid = blockIdx.x * TPB + threadIdx.x;
    if (tid >= NR * JQ) return;
    int jq = tid % JQ;
    int r = tid / JQ;
    int deg = cnt[RBASE + r];
    const int2* ep = ecv + (size_t)(RBASE + r) * CAP;
    float4 acc = make_float4(0.f, 0.f, 0.f, 0.f);
    for (int p = 0; p < deg; ++p) {
        int2 cv = ep[p];
        float v = __int_as_float(cv.y);
        float4 u = *reinterpret_cast<const float4*>(&up[(size_t)cv.x * BC + jq * 4]);
        acc.x = fmaf(v, u.x, acc.x);
        acc.y = fmaf(v, u.y, acc.y);
        acc.z = fmaf(v, u.z, acc.z);
        acc.w = fmaf(v, u.w, acc.w);
    }
    int col0 = jq * 4;
    float a[4] = {acc.x, acc.y, acc.z, acc.w};
#pragma unroll
    for (int e = 0; e < 4; ++e) {
        int col = col0 + e;
        int b = col / 3, j = col - b * 3;
        out[(size_t)b * 49152 + (size_t)r * 3 + j] = fmaxf(a[e] + bias[j], 0.f);
    }
}

extern "C" void kernel_launch(void* const* d_in, const int* in_sizes, int n_in,
                              void* d_out, int out_size, void* d_ws, size_t ws_size,
                              hipStream_t stream)
{
    const float* lat   = (const float*)d_in[0];
    const float* fcW   = (const float*)d_in[1];
    const float* fcb   = (const float*)d_in[2];
    const float* U0    = (const float*)d_in[3];
    const float* Ub0   = (const float*)d_in[4];
    const float* W0    = (const float*)d_in[5];
    const float* b0    = (const float*)d_in[6];
    const float* vals0 = (const float*)d_in[7];
    const int*   rows0 = (const int*)d_in[8];
    const int*   cols0 = (const int*)d_in[9];
    const float* U1    = (const float*)d_in[10];
    const float* Ub1   = (const float*)d_in[11];
    const float* W1    = (const float*)d_in[12];
    const float* b1    = (const float*)d_in[13];
    const float* vals1 = (const float*)d_in[14];
    const int*   rows1 = (const int*)d_in[15];
    const int*   cols1 = (const int*)d_in[16];
    const float* U2    = (const float*)d_in[17];
    const float* Ub2   = (const float*)d_in[18];
    const float* W2    = (const float*)d_in[19];
    const float* b2    = (const float*)d_in[20];
    const float* vals2 = (const float*)d_in[21];
    const int*   rows2 = (const int*)d_in[22];
    const int*   cols2 = (const int*)d_in[23];

    float* ws = (float*)d_ws;
    float* fbuf0 = ws;                      // 131072 (fc output)
    float* fWq   = fbuf0 + 131072;          // 262144 (frag buffer storage)
    float* UbW   = fWq   + 262144;          // 131072
    float* up    = UbW   + 131072;          // 1048576
    int*   cnt   = (int*)(up + 1048576);    // 21760 (+pad to 8B align)
    int2*  ecv   = (int2*)(cnt + 21764);    // 21504*128 int2 = 22 MB

    ushort* Fq16 = (ushort*)fWq;
    float* out = (float*)d_out;

    // 1: fc + cnt-zero
    hipLaunchKernelGGL(k_prep, dim3(596), dim3(TPB), 0, stream, lat, fcW, fcb, fbuf0, cnt);
    // 2: bucket build (packed) + fold0 + UbW0
    hipLaunchKernelGGL(k_build, dim3(2112), dim3(TPB), 0, stream,
                       rows0, cols0, vals0, rows1, cols1, vals1, rows2, cols2, vals2,
                       cnt, ecv, fbuf0, W0, Ub0, Fq16, UbW);
    // 3: layer-0 GEMM: M=1024 K=256 NTOT=512, CF=8 RF=1 PIPE=2 -> grid (64,4)
    hipLaunchKernelGGL((k_gemm_ws<256, 512, 64, 8, 1, 2>), dim3(64, 4), dim3(TPB), 0, stream,
                       U0, Fq16, UbW, up);
    // 4: fused gather0 + fold1  (NPB=1: 1024 blocks + 512 tail UbW1)
    hipLaunchKernelGGL((k_gf<1, 512, 64, 32, 256, 1024, 1024, 0, 4096>),
                       dim3(1536), dim3(TPB), 0, stream,
                       up, cnt, ecv, b0, W1, Ub1, Fq16, UbW);
    // 5: layer-1 GEMM: M=4096 K=1024 NTOT=256, CF=8 RF=1 PIPE=2 -> grid (256,2)
    hipLaunchKernelGGL((k_gemm_ws<1024, 256, 32, 8, 1, 2>), dim3(256, 2), dim3(TPB), 0, stream,
                       U1, Fq16, UbW, up);
    // 6: fused gather1 + fold2  (NPB=8: 512 blocks + 192 tail UbW2)
    hipLaunchKernelGGL((k_gf<8, 256, 32, 3, 32, 4096, 4096, 1024, 16384>),
                       dim3(704), dim3(TPB), 0, stream,
                       up, cnt, ecv, b1, W2, Ub2, Fq16, UbW);
    // 7: layer-2 GEMM: M=16384 K=4096 NTOT=24(pad32), CF=2 RF=2 PIPE=3 -> grid (512,1)
    hipLaunchKernelGGL((k_gemm_ws<4096, 24, 3, 2, 2, 3>), dim3(512, 1), dim3(TPB), 0, stream,
                       U2, Fq16, UbW, up);
    // 8: final gather + relu + bias + transpose
    hipLaunchKernelGGL((k_gather_out<24, 3, 16384, 5120>), dim3(384), dim3(TPB), 0, stream,
                       up, cnt, ecv, b2, out);
}

// Round 14
// 153.581 us; speedup vs baseline: 4.6055x; 1.0154x over previous
//
#include <hip/hip_runtime.h>
#include <cstdint>
#include <cstddef>

#define TPB 256
#define CAP 128   // bucket capacity per node (mean degree 16)

typedef __bf16 bf16x8 __attribute__((ext_vector_type(8)));
typedef float f32x4 __attribute__((ext_vector_type(4)));

union FragU { ushort u[8]; uint4 q; bf16x8 v; };

__device__ __forceinline__ ushort f2bf(float f)
{
    union { float f; uint32_t u; } v; v.f = f;
    uint32_t r = v.u + 0x7FFFu + ((v.u >> 16) & 1u);   // RNE
    return (ushort)(r >> 16);
}

// prep: fc (blocks 0..511) + zero cnt (blocks 512..595)
__global__ __launch_bounds__(TPB) void k_prep(
    const float* __restrict__ lat, const float* __restrict__ W,
    const float* __restrict__ bias, float* __restrict__ out,
    int* __restrict__ cnt)
{
    int bx = blockIdx.x;
    if (bx < 512) {
        int tid = bx * TPB + threadIdx.x;   // 131072
        int c = tid & 63;
        int b = (tid >> 6) & 7;
        int n = tid >> 9;
        int j = n * 64 + c;
        float acc = bias[j];
        const float* lb = lat + b * 64;
#pragma unroll 16
        for (int l = 0; l < 64; ++l)
            acc = fmaf(lb[l], W[l * 16384 + j], acc);
        out[tid] = acc;
    } else {
        int tid = (bx - 512) * TPB + threadIdx.x;
        if (tid < 21504) cnt[tid] = 0;
    }
}

// build: blocks [0,1344) bucket-fill all 3 edge lists (packed int2);
//        blocks [1344,1856) fold0 F-frags; [1856,2112) UbW0 tail.
__global__ __launch_bounds__(TPB) void k_build(
    const int* __restrict__ r0, const int* __restrict__ c0, const float* __restrict__ v0,
    const int* __restrict__ r1, const int* __restrict__ c1, const float* __restrict__ v1,
    const int* __restrict__ r2, const int* __restrict__ c2, const float* __restrict__ v2,
    int* __restrict__ cnt, int2* __restrict__ ecv,
    const float* __restrict__ X, const float* __restrict__ W0,
    const float* __restrict__ Ub0,
    ushort* __restrict__ Fq, float* __restrict__ UbW)
{
    int bx = blockIdx.x;
    if (bx < 1344) {
        int e = bx * TPB + threadIdx.x;
        int node, col; float val;
        if (e < 16384)       { node = r0[e];                col = c0[e];  val = v0[e]; }
        else if (e < 81920)  { int l = e - 16384; node = 1024 + r1[l]; col = c1[l]; val = v1[l]; }
        else                 { int l = e - 81920; node = 5120 + r2[l]; col = c2[l]; val = v2[l]; }
        int pos = atomicAdd(&cnt[node], 1);
        ecv[(size_t)node * CAP + pos] = make_int2(col, __float_as_int(val));
    } else if (bx < 1856) {
        // fold0: F = feat0@W0 in MFMA B-frag order, CI=64 CO=64 KF=256
        int tid = (bx - 1344) * TPB + threadIdx.x;
        int co = tid % 64;
        int nb = tid / 64;
        const float* x = X + (size_t)nb * 64;
        float acc = 0.f;
#pragma unroll
        for (int ci = 0; ci < 64; ++ci)
            acc = fmaf(x[ci], W0[ci * 64 + co], acc);
        int n = nb >> 3, bb = nb & 7;
        int col = bb * 64 + co;
        int ks = n >> 5, r = n & 31, kq = r >> 3, j = r & 7;
        int ct = col >> 4, cl = col & 15;
        size_t idx = ((((size_t)ct * (256 / 32) + ks) * 4 + kq) * 16 + cl) * 8 + j;
        Fq[idx] = f2bf(acc);
    } else {
        int tid = (bx - 1856) * TPB + threadIdx.x;
        if (tid >= 65536) return;
        int co = tid % 64;
        int row = tid / 64;
        const float* x = Ub0 + (size_t)row * 64;
        float acc = 0.f;
#pragma unroll
        for (int ci = 0; ci < 64; ++ci)
            acc = fmaf(x[ci], W0[ci * 64 + co], acc);
        UbW[tid] = acc;
    }
}

// ---------------- fused gather + relu/bias + fold-to-frags ----------------
// NPB nodes per block; TPN=TPB/NPB threads per node; CPT=BCIN/TPN ch/thread.
// Gather: edge loop OUTER, unrolled channel FMA inner (CPT-wide ILP).
// Fold: NPB*COLS outputs, all lanes active.
template<int NPB, int BCIN, int CI, int CO, int COLS, int KF,
         int NNODE, int RBASE, int NBUB>
__global__ __launch_bounds__(TPB) void k_gf(
    const float* __restrict__ up, const int* __restrict__ cnt,
    const int2* __restrict__ ecv,
    const float* __restrict__ bias, const float* __restrict__ W,
    const float* __restrict__ Ub,
    ushort* __restrict__ Fq, float* __restrict__ UbW)
{
    constexpr int TPN = TPB / NPB;
    constexpr int CPT = BCIN / TPN;
    int bx = blockIdx.x;
    if (bx < NNODE / NPB) {
        __shared__ float feat[NPB * BCIN];
        __shared__ float Wl[CI * CO];
        const int tid = threadIdx.x;
#pragma unroll
        for (int i = tid; i < CI * CO; i += TPB) Wl[i] = W[i];

        const int ni = tid / TPN;
        const int li = tid % TPN;
        const int node = bx * NPB + ni;
        const int deg = cnt[RBASE + node];
        const int2* ep = ecv + (size_t)(RBASE + node) * CAP;

        float acc[CPT];
#pragma unroll
        for (int k = 0; k < CPT; ++k) acc[k] = 0.f;
        for (int p = 0; p < deg; ++p) {
            int2 cv = ep[p];                       // broadcast within TPN group
            float v = __int_as_float(cv.y);
            const float* ur = up + (size_t)cv.x * BCIN + li;
#pragma unroll
            for (int k = 0; k < CPT; ++k)
                acc[k] = fmaf(v, ur[k * TPN], acc[k]);
        }
#pragma unroll
        for (int k = 0; k < CPT; ++k) {
            int c = li + k * TPN;
            feat[ni * BCIN + c] = fmaxf(acc[k] + bias[c % CI], 0.f);
        }
        __syncthreads();

#pragma unroll
        for (int e = tid; e < NPB * COLS; e += TPB) {
            int fni = e / COLS;
            int colp = e % COLS;
            int n = bx * NPB + fni;
            float a = 0.f;
            if (colp < 8 * CO) {
                int b = colp / CO, co = colp % CO;
                const float* fb = feat + fni * BCIN + b * CI;
#pragma unroll
                for (int ci = 0; ci < CI; ++ci)
                    a = fmaf(fb[ci], Wl[ci * CO + co], a);
            }
            int ks = n >> 5, rr = n & 31, kq = rr >> 3, j = rr & 7;
            int ct = colp >> 4, cl = colp & 15;
            size_t idx = ((((size_t)ct * (KF / 32) + ks) * 4 + kq) * 16 + cl) * 8 + j;
            Fq[idx] = f2bf(a);
        }
    } else {
        int tid = (bx - NNODE / NPB) * TPB + threadIdx.x;
        if (tid >= NBUB * CO) return;
        int co = tid % CO;
        int row = tid / CO;
        const float* x = Ub + (size_t)row * CI;
        float acc = 0.f;
#pragma unroll
        for (int ci = 0; ci < CI; ++ci)
            acc = fmaf(x[ci], W[ci * CO + co], acc);
        UbW[tid] = acc;
    }
}

// ---------------- LDS-free MFMA GEMM, intra-block wave K-split ----------------
template<int K, int NTOT, int CO, int CF, int RF>
__global__ __launch_bounds__(TPB) void k_gemm_ws(
    const float* __restrict__ U, const ushort* __restrict__ Fq,
    const float* __restrict__ UbW, float* __restrict__ up)
{
    constexpr int KCH = K / 4;
    constexpr int KS = KCH / 32;
    constexpr int NC = CF * 16;
    constexpr int RED = RF * NC * 16;
    static_assert(KS % 2 == 0, "even k-steps");

    __shared__ float red[4][RED];

    const int tid = threadIdx.x;
    const int lane = tid & 63;
    const int w = tid >> 6;
    const int rowbase = blockIdx.x * (RF * 16);
    const int jt = blockIdx.y;
    const int kq = lane >> 4;
    const int m = lane & 15;

    const float* Ap[RF];
#pragma unroll
    for (int rf = 0; rf < RF; ++rf)
        Ap[rf] = U + (size_t)(rowbase + rf * 16 + m) * K + w * KCH + kq * 8;

    const ushort* Bp[CF];
#pragma unroll
    for (int cf = 0; cf < CF; ++cf)
        Bp[cf] = Fq + ((size_t)(jt * CF + cf) * (K / 32) + (size_t)w * KS) * 512
                 + lane * 8;

    f32x4 acc[RF][CF];
#pragma unroll
    for (int rf = 0; rf < RF; ++rf)
#pragma unroll
        for (int cf = 0; cf < CF; ++cf)
            acc[rf][cf] = (f32x4){0.f, 0.f, 0.f, 0.f};

    float4 a[2][RF][2];
    uint4  b[2][CF];

#define LOAD_STEP(S, t)                                                     \
    if ((t) < KS) {                                                         \
        _Pragma("unroll")                                                   \
        for (int rf = 0; rf < RF; ++rf) {                                   \
            a[S][rf][0] = *reinterpret_cast<const float4*>(Ap[rf] + (t) * 32);     \
            a[S][rf][1] = *reinterpret_cast<const float4*>(Ap[rf] + (t) * 32 + 4); \
        }                                                                   \
        _Pragma("unroll")                                                   \
        for (int cf = 0; cf < CF; ++cf)                                     \
            b[S][cf] = *reinterpret_cast<const uint4*>(Bp[cf] + (t) * 512); \
    }

#define COMP_STEP(S)                                                        \
    {                                                                       \
        _Pragma("unroll")                                                   \
        for (int rf = 0; rf < RF; ++rf) {                                   \
            const float* fa = reinterpret_cast<const float*>(&a[S][rf][0]); \
            bf16x8 av;                                                      \
            _Pragma("unroll")                                               \
            for (int j = 0; j < 8; ++j) av[j] = (__bf16)fa[j];              \
            _Pragma("unroll")                                               \
            for (int cf = 0; cf < CF; ++cf) {                               \
                FragU bfr; bfr.q = b[S][cf];                                \
                acc[rf][cf] = __builtin_amdgcn_mfma_f32_16x16x32_bf16(      \
                    av, bfr.v, acc[rf][cf], 0, 0, 0);                       \
            }                                                               \
        }                                                                   \
    }

    LOAD_STEP(0, 0)
#pragma unroll
    for (int t = 0; t < KS; t += 2) {
        LOAD_STEP(1, t + 1)
        COMP_STEP(0)
        LOAD_STEP(0, t + 2)
        COMP_STEP(1)
    }
#undef LOAD_STEP
#undef COMP_STEP

#pragma unroll
    for (int rf = 0; rf < RF; ++rf)
#pragma unroll
        for (int cf = 0; cf < CF; ++cf)
#pragma unroll
            for (int r = 0; r < 4; ++r)
                red[w][(rf * NC + cf * 16 + m) * 16 + kq * 4 + r] = acc[rf][cf][r];
    __syncthreads();

#pragma unroll
    for (int e = tid; e < RED; e += TPB) {
        int rf = e / (NC * 16);
        int rem = e - rf * (NC * 16);
        int col = rem >> 4, row = rem & 15;
        float v = red[0][e] + red[1][e] + red[2][e] + red[3][e];
        int gcol = jt * NC + col;
        int grow = rowbase + rf * 16 + row;
        if (gcol < NTOT)
            up[(size_t)grow * NTOT + gcol] =
                v + UbW[(size_t)grow * CO + gcol % CO];
    }
}

// ---------------- final gather: relu+bias + output transpose ----------------
template<int BC, int CO, int NR, int RBASE>
__global__ __launch_bounds__(TPB) void k_gather_out(
    const float* __restrict__ up, const int* __restrict__ cnt,
    const int2* __restrict__ ecv,
    const float* __restrict__ bias, float* __restrict__ out)
{
    constexpr int JQ = BC / 4;
    int tid = blockIdx.x * TPB + threadIdx.x;
    if (tid >= NR * JQ) return;
    int jq = tid % JQ;
    int r = tid / JQ;
    int deg = cnt[RBASE + r];
    const int2* ep = ecv + (size_t)(RBASE + r) * CAP;
    float4 acc = make_float4(0.f, 0.f, 0.f, 0.f);
    for (int p = 0; p < deg; ++p) {
        int2 cv = ep[p];
        float v = __int_as_float(cv.y);
        float4 u = *reinterpret_cast<const float4*>(&up[(size_t)cv.x * BC + jq * 4]);
        acc.x = fmaf(v, u.x, acc.x);
        acc.y = fmaf(v, u.y, acc.y);
        acc.z = fmaf(v, u.z, acc.z);
        acc.w = fmaf(v, u.w, acc.w);
    }
    int col0 = jq * 4;
    float a[4] = {acc.x, acc.y, acc.z, acc.w};
#pragma unroll
    for (int e = 0; e < 4; ++e) {
        int col = col0 + e;
        int b = col / 3, j = col - b * 3;
        out[(size_t)b * 49152 + (size_t)r * 3 + j] = fmaxf(a[e] + bias[j], 0.f);
    }
}

extern "C" void kernel_launch(void* const* d_in, const int* in_sizes, int n_in,
                              void* d_out, int out_size, void* d_ws, size_t ws_size,
                              hipStream_t stream)
{
    const float* lat   = (const float*)d_in[0];
    const float* fcW   = (const float*)d_in[1];
    const float* fcb   = (const float*)d_in[2];
    const float* U0    = (const float*)d_in[3];
    const float* Ub0   = (const float*)d_in[4];
    const float* W0    = (const float*)d_in[5];
    const float* b0    = (const float*)d_in[6];
    const float* vals0 = (const float*)d_in[7];
    const int*   rows0 = (const int*)d_in[8];
    const int*   cols0 = (const int*)d_in[9];
    const float* U1    = (const float*)d_in[10];
    const float* Ub1   = (const float*)d_in[11];
    const float* W1    = (const float*)d_in[12];
    const float* b1    = (const float*)d_in[13];
    const float* vals1 = (const float*)d_in[14];
    const int*   rows1 = (const int*)d_in[15];
    const int*   cols1 = (const int*)d_in[16];
    const float* U2    = (const float*)d_in[17];
    const float* Ub2   = (const float*)d_in[18];
    const float* W2    = (const float*)d_in[19];
    const float* b2    = (const float*)d_in[20];
    const float* vals2 = (const float*)d_in[21];
    const int*   rows2 = (const int*)d_in[22];
    const int*   cols2 = (const int*)d_in[23];

    float* ws = (float*)d_ws;
    float* fbuf0 = ws;                      // 131072 (fc output)
    float* fWq   = fbuf0 + 131072;          // 262144 (frag buffer storage)
    float* UbW   = fWq   + 262144;          // 131072
    float* up    = UbW   + 131072;          // 1048576
    int*   cnt   = (int*)(up + 1048576);    // 21760 (+pad to 8B align)
    int2*  ecv   = (int2*)(cnt + 21764);    // 21504*128 int2 = 22 MB

    ushort* Fq16 = (ushort*)fWq;
    float* out = (float*)d_out;

    // 1: fc + cnt-zero
    hipLaunchKernelGGL(k_prep, dim3(596), dim3(TPB), 0, stream, lat, fcW, fcb, fbuf0, cnt);
    // 2: bucket build (packed) + fold0 + UbW0
    hipLaunchKernelGGL(k_build, dim3(2112), dim3(TPB), 0, stream,
                       rows0, cols0, vals0, rows1, cols1, vals1, rows2, cols2, vals2,
                       cnt, ecv, fbuf0, W0, Ub0, Fq16, UbW);
    // 3: layer-0 GEMM: M=1024 K=256 NTOT=512, CF=8 RF=1 -> grid (64,4)
    hipLaunchKernelGGL((k_gemm_ws<256, 512, 64, 8, 1>), dim3(64, 4), dim3(TPB), 0, stream,
                       U0, Fq16, UbW, up);
    // 4: fused gather0 + fold1  (NPB=1: 1024 blocks + 512 tail UbW1)
    hipLaunchKernelGGL((k_gf<1, 512, 64, 32, 256, 1024, 1024, 0, 4096>),
                       dim3(1536), dim3(TPB), 0, stream,
                       up, cnt, ecv, b0, W1, Ub1, Fq16, UbW);
    // 5: layer-1 GEMM: M=4096 K=1024 NTOT=256, CF=8 RF=1 -> grid (256,2)
    hipLaunchKernelGGL((k_gemm_ws<1024, 256, 32, 8, 1>), dim3(256, 2), dim3(TPB), 0, stream,
                       U1, Fq16, UbW, up);
    // 6: fused gather1 + fold2  (NPB=8: 512 blocks + 192 tail UbW2)
    hipLaunchKernelGGL((k_gf<8, 256, 32, 3, 32, 4096, 4096, 1024, 16384>),
                       dim3(704), dim3(TPB), 0, stream,
                       up, cnt, ecv, b1, W2, Ub2, Fq16, UbW);
    // 7: layer-2 GEMM: M=16384 K=4096 NTOT=24(pad32), CF=2 RF=2 -> grid (512,1)
    hipLaunchKernelGGL((k_gemm_ws<4096, 24, 3, 2, 2>), dim3(512, 1), dim3(TPB), 0, stream,
                       U2, Fq16, UbW, up);
    // 8: final gather + relu + bias + transpose
    hipLaunchKernelGGL((k_gather_out<24, 3, 16384, 5120>), dim3(384), dim3(TPB), 0, stream,
                       up, cnt, ecv, b2, out);
}